// Round 12
// baseline (263.755 us; speedup 1.0000x reference)
//
#include <hip/hip_runtime.h>
#include <hip/hip_bf16.h>
#include <math.h>

constexpr int T   = 1024;
constexpr int H   = 2048;
constexpr int I   = 1024;
constexpr int E   = 8;
constexpr int NEZ = 16;   // E + Z
constexpr int TK  = 4;    // TOP_K
constexpr int MTG = 24;   // max m-microtiles per expert (384 rows)

typedef short bf16x8 __attribute__((ext_vector_type(8)));
typedef float f32x4  __attribute__((ext_vector_type(4)));
typedef unsigned short u16;
typedef u16 u16x4 __attribute__((ext_vector_type(4)));
typedef u16 u16x8 __attribute__((ext_vector_type(8)));

__device__ __forceinline__ u16 bf16rn(float x) {
  unsigned u = __builtin_bit_cast(unsigned, x);
  u = u + 0x7FFFu + ((u >> 16) & 1u);
  return (u16)(u >> 16);
}
__device__ __forceinline__ float bf16tof(u16 h) {
  return __builtin_bit_cast(float, (unsigned)h << 16);
}

// ---------------------------------------------------------------------------
// Weight prep: convert+transpose into lane-ordered microtiles.
// Microtile (kt,ntg) = 1KB: lane L holds (n = ntg*16+(L&15), k = kt*32+(L>>4)*8+j).
// Plane layout [e][kt][ntg][64][8].
// ---------------------------------------------------------------------------
template <int KDIM, int NDIM>
__device__ __forceinline__ void prep_tile(
    const float* __restrict__ src, u16* __restrict__ dh, u16* __restrict__ dl,
    int ei, int kt, int nb)
{
  const int k0 = kt * 32, nn0 = nb * 64;
  __shared__ float Lt[32][65];
  const int tid = threadIdx.x;
#pragma unroll
  for (int r = 0; r < 2; r++) {
    const int f = tid + r * 256;
    const int k = f >> 4, nc = (f & 15) * 4;
    const float4 v = *(const float4*)(src + (size_t)(k0 + k) * NDIM + nn0 + nc);
    Lt[k][nc] = v.x; Lt[k][nc + 1] = v.y; Lt[k][nc + 2] = v.z; Lt[k][nc + 3] = v.w;
  }
  __syncthreads();

  const int w = tid >> 6, lane = tid & 63;
  const int l15 = lane & 15, lg = lane >> 4;
  const int ntg = (nn0 >> 4) + w;
  u16x8 h8, l8;
#pragma unroll
  for (int j = 0; j < 8; j++) {
    const float v = Lt[lg * 8 + j][w * 16 + l15];
    const u16 hh = bf16rn(v);
    h8[j] = hh;
    l8[j] = bf16rn(v - bf16tof(hh));
  }
  const size_t base =
      ((size_t)((size_t)ei * (KDIM >> 5) + kt) * (NDIM >> 4) + ntg) * 512 +
      (size_t)lane * 8;
  *(u16x8*)(dh + base) = h8;
  *(u16x8*)(dl + base) = l8;
}

__global__ __launch_bounds__(256) void prep_gu_kernel(
    const float* __restrict__ wg, const float* __restrict__ wu,
    u16* __restrict__ bgh, u16* __restrict__ bgl,
    u16* __restrict__ buh, u16* __restrict__ bul)
{
  const int z = blockIdx.y;
  const float* src; u16 *dh, *dl;
  if (z < 8) { src = wg + (size_t)z * H * I;       dh = bgh; dl = bgl; }
  else       { src = wu + (size_t)(z - 8) * H * I; dh = buh; dl = bul; }
  prep_tile<H, I>(src, dh, dl, z & 7, blockIdx.x >> 4, blockIdx.x & 15);
}

__global__ __launch_bounds__(256) void prep_d_kernel(
    const float* __restrict__ wd, u16* __restrict__ bdh, u16* __restrict__ bdl)
{
  const int ei = blockIdx.y;
  prep_tile<I, H>(wd + (size_t)ei * I * H, bdh, bdl, ei,
                  blockIdx.x >> 5, blockIdx.x & 31);
}

// ---------------------------------------------------------------------------
// prep_a: gather+convert x rows per expert into microtile planes
// Axh/Axl [e][kt=64][mtg=MTG][64][8].
// ---------------------------------------------------------------------------
__global__ __launch_bounds__(256) void prep_a_kernel(
    const float* __restrict__ x, const int* __restrict__ cnt,
    const int* __restrict__ list, u16* __restrict__ Axh, u16* __restrict__ Axl)
{
  const int kt = blockIdx.x;   // 0..63
  const int e  = blockIdx.y;   // 0..7
  int ce = cnt[e]; if (ce > MTG * 16) ce = MTG * 16;
  if (ce == 0) return;
  const int tid = threadIdx.x;
  const int w = tid >> 6, lane = tid & 63;
  const int l15 = lane & 15, lg = lane >> 4;

  for (int mtg = w; mtg < MTG; mtg += 4) {
    int r = mtg * 16 + l15; if (r >= ce) r = ce - 1;
    const int tok = list[e * T + r] >> 2;
    const float* src = x + (size_t)tok * H + kt * 32 + lg * 8;
    const float4 v0 = *(const float4*)(src);
    const float4 v1 = *(const float4*)(src + 4);
    const float vv[8] = {v0.x, v0.y, v0.z, v0.w, v1.x, v1.y, v1.z, v1.w};
    u16x8 h8, l8;
#pragma unroll
    for (int j = 0; j < 8; j++) {
      const u16 hh = bf16rn(vv[j]);
      h8[j] = hh;
      l8[j] = bf16rn(vv[j] - bf16tof(hh));
    }
    const size_t off = (((size_t)e * 64 + kt) * MTG + mtg) * 512 + (size_t)lane * 8;
    *(u16x8*)(Axh + off) = h8;
    *(u16x8*)(Axl + off) = l8;
  }
}

// ---------------------------------------------------------------------------
// Router (unchanged, fp32-exact selection).
// ---------------------------------------------------------------------------
__global__ __launch_bounds__(256) void router_kernel(
    const float* __restrict__ x, const float* __restrict__ rw,
    const float* __restrict__ bias, int* __restrict__ cnt,
    int* __restrict__ list, float* __restrict__ wk4,
    float* __restrict__ zerow)
{
  const int t   = blockIdx.x;
  const int tid = threadIdx.x;
  const float* xt = x + (size_t)t * H;

  float acc[NEZ];
#pragma unroll
  for (int e = 0; e < NEZ; e++) acc[e] = 0.f;

  for (int h = tid; h < H; h += 256) {
    const float xv = xt[h];
#pragma unroll
    for (int e = 0; e < NEZ; e++) acc[e] = fmaf(xv, rw[e * H + h], acc[e]);
  }

#pragma unroll
  for (int e = 0; e < NEZ; e++) {
    float v = acc[e];
#pragma unroll
    for (int off = 32; off >= 1; off >>= 1) v += __shfl_down(v, off, 64);
    acc[e] = v;
  }

  __shared__ float red[4][NEZ];
  const int wv = tid >> 6, ln = tid & 63;
  if (ln == 0) {
#pragma unroll
    for (int e = 0; e < NEZ; e++) red[wv][e] = acc[e];
  }
  __syncthreads();

  if (tid == 0) {
    float l[NEZ];
    float mx = -1e30f;
#pragma unroll
    for (int e = 0; e < NEZ; e++) {
      l[e] = red[0][e] + red[1][e] + red[2][e] + red[3][e];
      mx = fmaxf(mx, l[e]);
    }
    float s = 0.f;
#pragma unroll
    for (int e = 0; e < NEZ; e++) { l[e] = expf(l[e] - mx); s += l[e]; }
    const float inv = 1.f / s;
    float sc[NEZ], sel[NEZ];
#pragma unroll
    for (int e = 0; e < NEZ; e++) {
      sc[e]  = l[e] * inv;
      sel[e] = sc[e] + bias[e];
    }
    float zw = 0.f;
#pragma unroll
    for (int k = 0; k < TK; k++) {
      int best = 0; float bv = sel[0];
#pragma unroll
      for (int e = 1; e < NEZ; e++) {
        if (sel[e] > bv) { bv = sel[e]; best = e; }
      }
      sel[best] = -1e30f;
      const float w = sc[best];
      if (best < E) {
        const int pos = atomicAdd(&cnt[best], 1);
        list[best * T + pos] = (t << 2) | k;
        wk4[t * TK + k] = w;
      } else {
        wk4[t * TK + k] = 0.f;
        zw += w;
      }
    }
    zerow[t] = zw;
  }
}

// ---------------------------------------------------------------------------
// Gate+Up grouped GEMM — LDS-free loads, K-SPLIT x2. 512 thr = 8 waves:
// wave w -> (tier_local = w&3, kh = w>>2). kh=0 does kt 0..31, kh=1 kt 32..63
// of the SAME 64m x 32n tile; fp32 partials combined via LDS + 1 barrier.
// 2048 live wave-tasks = 2 waves/SIMD (was 1). Grid 512 = 8e x 32n x 2tg,
// XCD chunk == expert. Epilogue (kh=0): add partner acc, silu, microtiled mid.
// ---------------------------------------------------------------------------
__global__ __launch_bounds__(512, 2) void gateup_kernel(
    const u16* __restrict__ Axh, const u16* __restrict__ Axl,
    const u16* __restrict__ bgh, const u16* __restrict__ bgl,
    const u16* __restrict__ buh, const u16* __restrict__ bul,
    const int* __restrict__ cnt, const int* __restrict__ list,
    u16* __restrict__ midh, u16* __restrict__ midl)
{
  const int p = blockIdx.x;
  const int L = (p & 7) * 64 + (p >> 3);   // XCD chunk == expert
  const int e = L >> 6;
  const int rem = L & 63;
  const int n0 = (rem & 31) * 32;
  const int tg = rem >> 5;                 // tier group 0/1
  int ce = cnt[e]; if (ce > MTG * 16) ce = MTG * 16;
  if (ce == 0) return;
  const int ntiers = (ce + 63) >> 6;

  const int tid = threadIdx.x;
  const int w = tid >> 6, lane = tid & 63;
  const int l15 = lane & 15, lg = lane >> 4;
  const int tl = w & 3, kh = w >> 2;
  const int tier = tg * 4 + tl;
  const bool alive = (tier < ntiers);

  __shared__ float eplds[4][64][68];       // partial-acc exchange (padded)

  f32x4 accg[4][2] = {};
  f32x4 accu[4][2] = {};

  if (alive) {
    // B byte pointers; plane [e][kt=64][ntg=64][1KB]; this wave: kt base kh*32
    const size_t bo = ((size_t)(e * 64 + kh * 32) * 64 + (size_t)(n0 >> 4)) * 1024 +
                      (size_t)lane * 16;
    const char* pBgh = (const char*)bgh + bo;
    const char* pBgl = (const char*)bgl + bo;
    const char* pBuh = (const char*)buh + bo;
    const char* pBul = (const char*)bul + bo;

    // A byte pointers; plane [e][kt=64][mtg=MTG][1KB]
    const size_t ao = (((size_t)(e * 64 + kh * 32)) * MTG + (size_t)tier * 4) * 1024 +
                      (size_t)lane * 16;
    const char* pAh = (const char*)Axh + ao;
    const char* pAl = (const char*)Axl + ao;

    bf16x8 A0[8], B0[8], A1[8], B1[8];

#define GU_LOAD(As, Bs, kt_) do {                                         \
    const size_t ka = (size_t)(kt_) * (MTG * 1024);                       \
    const size_t kb = (size_t)(kt_) * 65536;                              \
    _Pragma("unroll") for (int q = 0; q < 4; q++) {                       \
      As[q]     = *(const bf16x8*)(pAh + ka + q * 1024);                  \
      As[4 + q] = *(const bf16x8*)(pAl + ka + q * 1024);                  \
    }                                                                     \
    _Pragma("unroll") for (int j = 0; j < 2; j++) {                       \
      Bs[j * 4 + 0] = *(const bf16x8*)(pBgh + kb + j * 1024);             \
      Bs[j * 4 + 1] = *(const bf16x8*)(pBgl + kb + j * 1024);             \
      Bs[j * 4 + 2] = *(const bf16x8*)(pBuh + kb + j * 1024);             \
      Bs[j * 4 + 3] = *(const bf16x8*)(pBul + kb + j * 1024);             \
    }                                                                     \
  } while (0)

#define GU_STEP(As, Bs) do {                                              \
    _Pragma("unroll") for (int ni = 0; ni < 2; ni++) {                    \
      _Pragma("unroll") for (int mi = 0; mi < 4; mi++) {                  \
        accg[mi][ni] = __builtin_amdgcn_mfma_f32_16x16x32_bf16(As[mi],     Bs[ni*4+0], accg[mi][ni], 0, 0, 0); \
        accg[mi][ni] = __builtin_amdgcn_mfma_f32_16x16x32_bf16(As[mi],     Bs[ni*4+1], accg[mi][ni], 0, 0, 0); \
        accg[mi][ni] = __builtin_amdgcn_mfma_f32_16x16x32_bf16(As[4 + mi], Bs[ni*4+0], accg[mi][ni], 0, 0, 0); \
        accu[mi][ni] = __builtin_amdgcn_mfma_f32_16x16x32_bf16(As[mi],     Bs[ni*4+2], accu[mi][ni], 0, 0, 0); \
        accu[mi][ni] = __builtin_amdgcn_mfma_f32_16x16x32_bf16(As[mi],     Bs[ni*4+3], accu[mi][ni], 0, 0, 0); \
        accu[mi][ni] = __builtin_amdgcn_mfma_f32_16x16x32_bf16(As[4 + mi], Bs[ni*4+2], accu[mi][ni], 0, 0, 0); \
      }                                                                   \
    }                                                                     \
  } while (0)

    GU_LOAD(A0, B0, 0);
    for (int t = 0; t < 32; t += 2) {
      GU_LOAD(A1, B1, t + 1);
      GU_STEP(A0, B0);
      if (t + 2 < 32) GU_LOAD(A0, B0, t + 2);
      GU_STEP(A1, B1);
    }
#undef GU_LOAD
#undef GU_STEP

    if (kh == 1) {
      // publish partial acc for the kh=0 partner
#pragma unroll
      for (int mi = 0; mi < 4; mi++)
#pragma unroll
        for (int ni = 0; ni < 2; ni++) {
          *(f32x4*)&eplds[tl][lane][(mi * 2 + ni) * 4]      = accg[mi][ni];
          *(f32x4*)&eplds[tl][lane][32 + (mi * 2 + ni) * 4] = accu[mi][ni];
        }
    }
  }

  __syncthreads();

  if (alive && kh == 0) {
#pragma unroll
    for (int mi = 0; mi < 4; mi++)
#pragma unroll
      for (int ni = 0; ni < 2; ni++) {
        accg[mi][ni] += *(const f32x4*)&eplds[tl][lane][(mi * 2 + ni) * 4];
        accu[mi][ni] += *(const f32x4*)&eplds[tl][lane][32 + (mi * 2 + ni) * 4];
      }

    // epilogue: silu(g)*u -> bf16 hi/lo mid in microtile layout [e][ktI][mtg][512]
#pragma unroll
    for (int mi = 0; mi < 4; mi++) {
#pragma unroll
      for (int rr = 0; rr < 4; rr++) {
        const int m = tier * 64 + mi * 16 + lg * 4 + rr;
        if (m >= ce) continue;
#pragma unroll
        for (int ni = 0; ni < 2; ni++) {
          const int n = n0 + ni * 16 + l15;
          const float g = accg[mi][ni][rr];
          const float u = accu[mi][ni][rr];
          const float mv = (g / (1.f + expf(-g))) * u;
          const u16 hh = bf16rn(mv);
          const size_t off =
              (((size_t)e * 32 + (n >> 5)) * MTG + (m >> 4)) * 512 +
              (size_t)((m & 15) + ((n >> 3) & 3) * 16) * 8 + (n & 7);
          midh[off] = hh;
          midl[off] = bf16rn(mv - bf16tof(hh));
        }
      }
    }
  }
}

// ---------------------------------------------------------------------------
// Down grouped GEMM — LDS-free. Wave tile 64m x 32n; 2048 wave-tasks
// (4 tiers x 64 n-units x 8 e) = 2 waves/SIMD. Grid 1024 = 8e x 64n x 2tg,
// 256 thr (tier = tg*4 + w). 24 MFMA / 12 loads per step, 32 steps.
// ---------------------------------------------------------------------------
__global__ __launch_bounds__(256, 2) void down_kernel(
    const u16* __restrict__ midh, const u16* __restrict__ midl,
    const u16* __restrict__ bdh, const u16* __restrict__ bdl,
    const int* __restrict__ cnt, const int* __restrict__ list,
    float* __restrict__ downb)
{
  const int p = blockIdx.x;
  const int L = (p & 7) * 128 + (p >> 3);
  const int e = L >> 7;
  const int rem = L & 127;
  const int n0 = (rem & 63) * 32;
  const int tg = rem >> 6;
  int ce = cnt[e]; if (ce > MTG * 16) ce = MTG * 16;
  if (ce == 0) return;
  const int ntiers = (ce + 63) >> 6;

  const int tid = threadIdx.x;
  const int w = tid >> 6, lane = tid & 63;
  const int l15 = lane & 15, lg = lane >> 4;

  const int tier = tg * 4 + w;
  if (tier >= ntiers) return;

  // B pointers; plane [e][kt=32][ntg=128][1KB]; per-kt stride 131072 B
  const size_t bo = ((size_t)e * 32 * 128 + (size_t)(n0 >> 4)) * 1024 + (size_t)lane * 16;
  const char* pBh = (const char*)bdh + bo;
  const char* pBl = (const char*)bdl + bo;

  // A (mid) pointers; per-kt stride = MTG * 1KB
  const size_t ao = (((size_t)e * 32) * MTG + (size_t)tier * 4) * 1024 + (size_t)lane * 16;
  const char* pAh = (const char*)midh + ao;
  const char* pAl = (const char*)midl + ao;

  f32x4 acc[4][2] = {};

  bf16x8 A0[8], B0[4], A1[8], B1[4];

#define DN_LOAD(As, Bs, kt_) do {                                         \
    const size_t ka = (size_t)(kt_) * (MTG * 1024);                       \
    const size_t kb = (size_t)(kt_) * 131072;                             \
    _Pragma("unroll") for (int q = 0; q < 4; q++) {                       \
      As[q]     = *(const bf16x8*)(pAh + ka + q * 1024);                  \
      As[4 + q] = *(const bf16x8*)(pAl + ka + q * 1024);                  \
    }                                                                     \
    _Pragma("unroll") for (int j = 0; j < 2; j++) {                       \
      Bs[j * 2 + 0] = *(const bf16x8*)(pBh + kb + j * 1024);              \
      Bs[j * 2 + 1] = *(const bf16x8*)(pBl + kb + j * 1024);              \
    }                                                                     \
  } while (0)

#define DN_STEP(As, Bs) do {                                              \
    _Pragma("unroll") for (int ni = 0; ni < 2; ni++) {                    \
      _Pragma("unroll") for (int mi = 0; mi < 4; mi++) {                  \
        acc[mi][ni] = __builtin_amdgcn_mfma_f32_16x16x32_bf16(As[mi],     Bs[ni*2+0], acc[mi][ni], 0, 0, 0); \
        acc[mi][ni] = __builtin_amdgcn_mfma_f32_16x16x32_bf16(As[mi],     Bs[ni*2+1], acc[mi][ni], 0, 0, 0); \
        acc[mi][ni] = __builtin_amdgcn_mfma_f32_16x16x32_bf16(As[4 + mi], Bs[ni*2+0], acc[mi][ni], 0, 0, 0); \
      }                                                                   \
    }                                                                     \
  } while (0)

  DN_LOAD(A0, B0, 0);
  for (int t = 0; t < 32; t += 2) {
    DN_LOAD(A1, B1, t + 1);
    DN_STEP(A0, B0);
    if (t + 2 < 32) DN_LOAD(A0, B0, t + 2);
    DN_STEP(A1, B1);
  }
#undef DN_LOAD
#undef DN_STEP

#pragma unroll
  for (int mi = 0; mi < 4; mi++) {
#pragma unroll
    for (int rr = 0; rr < 4; rr++) {
      const int m = tier * 64 + mi * 16 + lg * 4 + rr;
      if (m >= ce) continue;
      const int ent  = list[e * T + m];
      const int tok  = ent >> 2;
      const int slot = ent & 3;
      float* drow = downb + ((size_t)tok * TK + slot) * H;
#pragma unroll
      for (int ni = 0; ni < 2; ni++) {
        const int n = n0 + ni * 16 + l15;
        drow[n] = acc[mi][ni][rr];
      }
    }
  }
}

// ---------------------------------------------------------------------------
// Combine (unchanged).
// ---------------------------------------------------------------------------
__global__ __launch_bounds__(256) void combine_kernel(
    const float* __restrict__ x, const float* __restrict__ downb,
    const float* __restrict__ wk4, const float* __restrict__ zerow,
    float* __restrict__ out)
{
  const int idx = blockIdx.x * 256 + threadIdx.x;
  const int t   = idx >> 9;
  const int h   = (idx & 511) * 4;

  const float w0 = wk4[t * TK + 0];
  const float w1 = wk4[t * TK + 1];
  const float w2 = wk4[t * TK + 2];
  const float w3 = wk4[t * TK + 3];
  const float zw = zerow[t];

  const float4 xv = *(const float4*)(x + (size_t)t * H + h);
  const float4 d0 = *(const float4*)(downb + ((size_t)t * TK + 0) * H + h);
  const float4 d1 = *(const float4*)(downb + ((size_t)t * TK + 1) * H + h);
  const float4 d2 = *(const float4*)(downb + ((size_t)t * TK + 2) * H + h);
  const float4 d3 = *(const float4*)(downb + ((size_t)t * TK + 3) * H + h);

  float4 o;
  o.x = w0 * d0.x + w1 * d1.x + w2 * d2.x + w3 * d3.x + zw * xv.x;
  o.y = w0 * d0.y + w1 * d1.y + w2 * d2.y + w3 * d3.y + zw * xv.y;
  o.z = w0 * d0.z + w1 * d1.z + w2 * d2.z + w3 * d3.z + zw * xv.z;
  o.w = w0 * d0.w + w1 * d1.w + w2 * d2.w + w3 * d3.w + zw * xv.w;
  *(float4*)(out + (size_t)t * H + h) = o;
}

// ---------------------------------------------------------------------------
// Workspace (~172 MiB): Axh/Axl 12.6 MiB; P = 4 planes x 33.6 MiB
// (bgh/bgl/buh/bul -> later bdh=P0, bdl=P1, downb=P2); midh/midl 6.3 MiB.
// ---------------------------------------------------------------------------
extern "C" void kernel_launch(void* const* d_in, const int* in_sizes, int n_in,
                              void* d_out, int out_size, void* d_ws, size_t ws_size,
                              hipStream_t stream) {
  const float* x    = (const float*)d_in[0];
  const float* rw   = (const float*)d_in[1];
  const float* bias = (const float*)d_in[2];
  const float* wg   = (const float*)d_in[3];
  const float* wu   = (const float*)d_in[4];
  const float* wd   = (const float*)d_in[5];
  float* out = (float*)d_out;

  char* ws = (char*)d_ws;
  size_t off = 0;
  auto alloc = [&](size_t bytes) {
    void* p = ws + off;
    off = (off + bytes + 1023) & ~(size_t)1023;
    return p;
  };
  int*   cnt   = (int*)  alloc(E * sizeof(int));
  int*   list  = (int*)  alloc((size_t)E * T * sizeof(int));
  float* wk4   = (float*)alloc((size_t)T * TK * sizeof(float));
  float* zerow = (float*)alloc((size_t)T * sizeof(float));
  const size_t AXSZ = (size_t)E * 64 * MTG * 512;          // elems
  u16*   Axh   = (u16*)  alloc(AXSZ * sizeof(u16));
  u16*   Axl   = (u16*)  alloc(AXSZ * sizeof(u16));
  constexpr size_t PLANE = (size_t)E * H * I * sizeof(u16);  // 33.6 MB
  char*  P     = (char*) alloc(4 * PLANE);
  u16*   bgh   = (u16*)(P);
  u16*   bgl   = (u16*)(P + PLANE);
  u16*   buh   = (u16*)(P + 2 * PLANE);
  u16*   bul   = (u16*)(P + 3 * PLANE);
  u16*   bdh   = bgh;                      // alias: written after gateup
  u16*   bdl   = bgl;
  float* downb = (float*)(P + 2 * PLANE);  // alias buh: written during down
  const size_t MIDSZ = (size_t)E * 32 * MTG * 512;         // elems
  u16*   midh  = (u16*)  alloc(MIDSZ * sizeof(u16));
  u16*   midl  = (u16*)  alloc(MIDSZ * sizeof(u16));
  (void)ws_size;

  hipMemsetAsync(cnt, 0, E * sizeof(int), stream);

  router_kernel<<<T, 256, 0, stream>>>(x, rw, bias, cnt, list, wk4, zerow);
  prep_a_kernel<<<dim3(64, 8), 256, 0, stream>>>(x, cnt, list, Axh, Axl);
  prep_gu_kernel<<<dim3(1024, 16), 256, 0, stream>>>(
      wg, wu, bgh, bgl, buh, bul);

  gateup_kernel<<<512, 512, 0, stream>>>(
      Axh, Axl, bgh, bgl, buh, bul, cnt, list, midh, midl);

  prep_d_kernel<<<dim3(1024, 8), 256, 0, stream>>>(wd, bdh, bdl);

  down_kernel<<<1024, 256, 0, stream>>>(
      midh, midl, bdh, bdl, cnt, list, downb);
  combine_kernel<<<(T * H / 4) / 256, 256, 0, stream>>>(
      x, downb, wk4, zerow, out);
}

// Round 13
// 260.741 us; speedup vs baseline: 1.0116x; 1.0116x over previous
//
#include <hip/hip_runtime.h>
#include <hip/hip_bf16.h>
#include <math.h>

constexpr int T   = 1024;
constexpr int H   = 2048;
constexpr int I   = 1024;
constexpr int E   = 8;
constexpr int NEZ = 16;   // E + Z
constexpr int TK  = 4;    // TOP_K
constexpr int MTG = 24;   // max m-microtiles per expert (384 rows)

typedef short bf16x8 __attribute__((ext_vector_type(8)));
typedef float f32x4  __attribute__((ext_vector_type(4)));
typedef unsigned short u16;
typedef u16 u16x8 __attribute__((ext_vector_type(8)));

#define VMCNT(n) asm volatile("s_waitcnt vmcnt(" #n ")" ::: "memory")

__device__ __forceinline__ u16 bf16rn(float x) {
  unsigned u = __builtin_bit_cast(unsigned, x);
  u = u + 0x7FFFu + ((u >> 16) & 1u);
  return (u16)(u >> 16);
}
__device__ __forceinline__ float bf16tof(u16 h) {
  return __builtin_bit_cast(float, (unsigned)h << 16);
}

// async global->LDS, 16B per lane; LDS dest = wave-uniform base + lane*16
__device__ __forceinline__ void g2l16(const void* g, void* l) {
  __builtin_amdgcn_global_load_lds(
      (const __attribute__((address_space(1))) unsigned int*)g,
      (__attribute__((address_space(3))) unsigned int*)l, 16, 0, 0);
}

// ---------------------------------------------------------------------------
// Weight prep: convert+transpose into lane-ordered microtiles.
// Microtile (kt,ntg) = 1KB: lane L holds (n = ntg*16+(L&15), k = kt*32+(L>>4)*8+j).
// Plane layout [e][kt][ntg][64][8].
// ---------------------------------------------------------------------------
template <int KDIM, int NDIM>
__device__ __forceinline__ void prep_tile(
    const float* __restrict__ src, u16* __restrict__ dh, u16* __restrict__ dl,
    int ei, int kt, int nb)
{
  const int k0 = kt * 32, nn0 = nb * 64;
  __shared__ float Lt[32][65];
  const int tid = threadIdx.x;
#pragma unroll
  for (int r = 0; r < 2; r++) {
    const int f = tid + r * 256;
    const int k = f >> 4, nc = (f & 15) * 4;
    const float4 v = *(const float4*)(src + (size_t)(k0 + k) * NDIM + nn0 + nc);
    Lt[k][nc] = v.x; Lt[k][nc + 1] = v.y; Lt[k][nc + 2] = v.z; Lt[k][nc + 3] = v.w;
  }
  __syncthreads();

  const int w = tid >> 6, lane = tid & 63;
  const int l15 = lane & 15, lg = lane >> 4;
  const int ntg = (nn0 >> 4) + w;
  u16x8 h8, l8;
#pragma unroll
  for (int j = 0; j < 8; j++) {
    const float v = Lt[lg * 8 + j][w * 16 + l15];
    const u16 hh = bf16rn(v);
    h8[j] = hh;
    l8[j] = bf16rn(v - bf16tof(hh));
  }
  const size_t base =
      ((size_t)((size_t)ei * (KDIM >> 5) + kt) * (NDIM >> 4) + ntg) * 512 +
      (size_t)lane * 8;
  *(u16x8*)(dh + base) = h8;
  *(u16x8*)(dl + base) = l8;
}

__global__ __launch_bounds__(256) void prep_gu_kernel(
    const float* __restrict__ wg, const float* __restrict__ wu,
    u16* __restrict__ bgh, u16* __restrict__ bgl,
    u16* __restrict__ buh, u16* __restrict__ bul)
{
  const int z = blockIdx.y;
  const float* src; u16 *dh, *dl;
  if (z < 8) { src = wg + (size_t)z * H * I;       dh = bgh; dl = bgl; }
  else       { src = wu + (size_t)(z - 8) * H * I; dh = buh; dl = bul; }
  prep_tile<H, I>(src, dh, dl, z & 7, blockIdx.x >> 4, blockIdx.x & 15);
}

__global__ __launch_bounds__(256) void prep_d_kernel(
    const float* __restrict__ wd, u16* __restrict__ bdh, u16* __restrict__ bdl)
{
  const int ei = blockIdx.y;
  prep_tile<I, H>(wd + (size_t)ei * I * H, bdh, bdl, ei,
                  blockIdx.x >> 5, blockIdx.x & 31);
}

// ---------------------------------------------------------------------------
// prep_a: gather+convert x rows per expert into microtile planes
// Axh/Axl [e][kt=64][mtg=MTG][64][8].
// ---------------------------------------------------------------------------
__global__ __launch_bounds__(256) void prep_a_kernel(
    const float* __restrict__ x, const int* __restrict__ cnt,
    const int* __restrict__ list, u16* __restrict__ Axh, u16* __restrict__ Axl)
{
  const int kt = blockIdx.x;   // 0..63
  const int e  = blockIdx.y;   // 0..7
  int ce = cnt[e]; if (ce > MTG * 16) ce = MTG * 16;
  if (ce == 0) return;
  const int tid = threadIdx.x;
  const int w = tid >> 6, lane = tid & 63;
  const int l15 = lane & 15, lg = lane >> 4;

  for (int mtg = w; mtg < MTG; mtg += 4) {
    int r = mtg * 16 + l15; if (r >= ce) r = ce - 1;
    const int tok = list[e * T + r] >> 2;
    const float* src = x + (size_t)tok * H + kt * 32 + lg * 8;
    const float4 v0 = *(const float4*)(src);
    const float4 v1 = *(const float4*)(src + 4);
    const float vv[8] = {v0.x, v0.y, v0.z, v0.w, v1.x, v1.y, v1.z, v1.w};
    u16x8 h8, l8;
#pragma unroll
    for (int j = 0; j < 8; j++) {
      const u16 hh = bf16rn(vv[j]);
      h8[j] = hh;
      l8[j] = bf16rn(vv[j] - bf16tof(hh));
    }
    const size_t off = (((size_t)e * 64 + kt) * MTG + mtg) * 512 + (size_t)lane * 8;
    *(u16x8*)(Axh + off) = h8;
    *(u16x8*)(Axl + off) = l8;
  }
}

// ---------------------------------------------------------------------------
// Router (unchanged, fp32-exact selection).
// ---------------------------------------------------------------------------
__global__ __launch_bounds__(256) void router_kernel(
    const float* __restrict__ x, const float* __restrict__ rw,
    const float* __restrict__ bias, int* __restrict__ cnt,
    int* __restrict__ list, float* __restrict__ wk4,
    float* __restrict__ zerow)
{
  const int t   = blockIdx.x;
  const int tid = threadIdx.x;
  const float* xt = x + (size_t)t * H;

  float acc[NEZ];
#pragma unroll
  for (int e = 0; e < NEZ; e++) acc[e] = 0.f;

  for (int h = tid; h < H; h += 256) {
    const float xv = xt[h];
#pragma unroll
    for (int e = 0; e < NEZ; e++) acc[e] = fmaf(xv, rw[e * H + h], acc[e]);
  }

#pragma unroll
  for (int e = 0; e < NEZ; e++) {
    float v = acc[e];
#pragma unroll
    for (int off = 32; off >= 1; off >>= 1) v += __shfl_down(v, off, 64);
    acc[e] = v;
  }

  __shared__ float red[4][NEZ];
  const int wv = tid >> 6, ln = tid & 63;
  if (ln == 0) {
#pragma unroll
    for (int e = 0; e < NEZ; e++) red[wv][e] = acc[e];
  }
  __syncthreads();

  if (tid == 0) {
    float l[NEZ];
    float mx = -1e30f;
#pragma unroll
    for (int e = 0; e < NEZ; e++) {
      l[e] = red[0][e] + red[1][e] + red[2][e] + red[3][e];
      mx = fmaxf(mx, l[e]);
    }
    float s = 0.f;
#pragma unroll
    for (int e = 0; e < NEZ; e++) { l[e] = expf(l[e] - mx); s += l[e]; }
    const float inv = 1.f / s;
    float sc[NEZ], sel[NEZ];
#pragma unroll
    for (int e = 0; e < NEZ; e++) {
      sc[e]  = l[e] * inv;
      sel[e] = sc[e] + bias[e];
    }
    float zw = 0.f;
#pragma unroll
    for (int k = 0; k < TK; k++) {
      int best = 0; float bv = sel[0];
#pragma unroll
      for (int e = 1; e < NEZ; e++) {
        if (sel[e] > bv) { bv = sel[e]; best = e; }
      }
      sel[best] = -1e30f;
      const float w = sc[best];
      if (best < E) {
        const int pos = atomicAdd(&cnt[best], 1);
        list[best * T + pos] = (t << 2) | k;
        wk4[t * TK + k] = w;
      } else {
        wk4[t * TK + k] = 0.f;
        zw += w;
      }
    }
    zerow[t] = zw;
  }
}

// ---------------------------------------------------------------------------
// Gate+Up grouped GEMM — hybrid feed. 256 thr / 4 waves; BM=256 (wave = 64m
// tier), BN=32, BK=32. B staged ONCE per block via global_load_lds into
// 3 x 8KB buffers (2 deep, counted VMCNT(10), 1 barrier/step, stage AFTER
// the barrier). A direct global->VGPR ping-pong (L2-resident microtiles).
// 48 MFMA / step / wave. Grid 512 = 8e x 32nu x 2tg (tg=1 exits unless
// ntiers>4). XCD chunk == expert. Epilogue: silu -> microtiled mid.
// ---------------------------------------------------------------------------
__global__ __launch_bounds__(256, 2) void gateup_kernel(
    const u16* __restrict__ Axh, const u16* __restrict__ Axl,
    const u16* __restrict__ bgh, const u16* __restrict__ bgl,
    const u16* __restrict__ buh, const u16* __restrict__ bul,
    const int* __restrict__ cnt, const int* __restrict__ list,
    u16* __restrict__ midh, u16* __restrict__ midl)
{
  const int p = blockIdx.x;
  const int L = (p & 7) * 64 + (p >> 3);   // XCD chunk == expert
  const int e = L >> 6;
  const int rem = L & 63;
  const int nu = rem & 31;
  const int tg = rem >> 5;
  const int n0 = nu * 32;
  int ce = cnt[e]; if (ce > MTG * 16) ce = MTG * 16;
  if (ce == 0) return;
  const int ntiers = (ce + 63) >> 6;
  if (tg == 1 && ntiers <= 4) return;      // tail blocks usually dead

  __shared__ __align__(16) char ldsB[3 * 8192];

  const int tid = threadIdx.x;
  const int w = tid >> 6, lane = tid & 63;
  const int l15 = lane & 15, lg = lane >> 4;
  const int tier = tg * 4 + w;

  // A pointers (clamped; dead tiers produce unused garbage)
  int tbase = tier * 64;
  const size_t ao = (((size_t)e * 64) * MTG + (size_t)((tbase >> 4) < MTG ? (tbase >> 4) : MTG - 4) * 1) * 1024;
  const char* pAh = (const char*)Axh + (((size_t)e * 64) * MTG + (size_t)(tier < 6 ? tier * 4 : MTG - 4)) * 1024 + (size_t)lane * 16;
  const char* pAl = (const char*)Axl + (((size_t)e * 64) * MTG + (size_t)(tier < 6 ? tier * 4 : MTG - 4)) * 1024 + (size_t)lane * 16;
  (void)ao; (void)tbase;

  // B stage sources: wave w stages tiles idx = 2w, 2w+1:
  //   ntg = w>>1, planes: even wave -> (gh,gl), odd wave -> (uh,ul)
  const size_t bbase = (((size_t)e * 64) * 64 + (size_t)(n0 >> 4) + (size_t)(w >> 1)) * 1024 +
                       (size_t)lane * 16;
  const char* s0 = (const char*)((w & 1) ? buh : bgh) + bbase;
  const char* s1 = (const char*)((w & 1) ? bul : bgl) + bbase;
  const int d0 = w * 2048;                 // LDS dest for this wave's 2 tiles

  f32x4 accg[4][2] = {};
  f32x4 accu[4][2] = {};
  bf16x8 A0[8], A1[8];

  auto stageB = [&](int ts) {
    char* bb = ldsB + (ts % 3) * 8192;
    const size_t kb = (size_t)ts * 65536;  // 64 ntg * 1KB per kt
    g2l16(s0 + kb, bb + d0);
    g2l16(s1 + kb, bb + d0 + 1024);
  };
  auto aload = [&](bf16x8* As, int ts) {
    const size_t ka = (size_t)ts * (MTG * 1024);
#pragma unroll
    for (int q = 0; q < 4; q++) {
      As[q]     = *(const bf16x8*)(pAh + ka + q * 1024);
      As[4 + q] = *(const bf16x8*)(pAl + ka + q * 1024);
    }
  };
  auto compute = [&](const char* bp, bf16x8* As) {
    bf16x8 bgf[2][2], buf_[2][2];
#pragma unroll
    for (int ni = 0; ni < 2; ni++) {
      bgf[ni][0]  = *(const bf16x8*)(bp + (ni * 4 + 0) * 1024 + lane * 16);
      bgf[ni][1]  = *(const bf16x8*)(bp + (ni * 4 + 1) * 1024 + lane * 16);
      buf_[ni][0] = *(const bf16x8*)(bp + (ni * 4 + 2) * 1024 + lane * 16);
      buf_[ni][1] = *(const bf16x8*)(bp + (ni * 4 + 3) * 1024 + lane * 16);
    }
#pragma unroll
    for (int ni = 0; ni < 2; ni++)
#pragma unroll
      for (int mi = 0; mi < 4; mi++) {
        accg[mi][ni] = __builtin_amdgcn_mfma_f32_16x16x32_bf16(As[mi],     bgf[ni][0],  accg[mi][ni], 0, 0, 0);
        accg[mi][ni] = __builtin_amdgcn_mfma_f32_16x16x32_bf16(As[mi],     bgf[ni][1],  accg[mi][ni], 0, 0, 0);
        accg[mi][ni] = __builtin_amdgcn_mfma_f32_16x16x32_bf16(As[4 + mi], bgf[ni][0],  accg[mi][ni], 0, 0, 0);
        accu[mi][ni] = __builtin_amdgcn_mfma_f32_16x16x32_bf16(As[mi],     buf_[ni][0], accu[mi][ni], 0, 0, 0);
        accu[mi][ni] = __builtin_amdgcn_mfma_f32_16x16x32_bf16(As[mi],     buf_[ni][1], accu[mi][ni], 0, 0, 0);
        accu[mi][ni] = __builtin_amdgcn_mfma_f32_16x16x32_bf16(As[4 + mi], buf_[ni][0], accu[mi][ni], 0, 0, 0);
      }
  };

  // prologue: B(0), A(0), B(1)
  stageB(0);
  aload(A0, 0);
  stageB(1);

  for (int t = 0; t < 64; t += 2) {
    aload(A1, t + 1);
    VMCNT(10);                              // B(t) done; A(t+1)+B(t+1) in flight
    __builtin_amdgcn_s_barrier();
    if (t + 2 < 64) stageB(t + 2);
    compute(ldsB + (t % 3) * 8192, A0);

    if (t + 2 < 64) aload(A0, t + 2);
    if (t + 1 < 63) { VMCNT(10); } else { VMCNT(0); }
    __builtin_amdgcn_s_barrier();
    if (t + 3 < 64) stageB(t + 3);
    compute(ldsB + ((t + 1) % 3) * 8192, A1);
  }

  // epilogue: silu(g)*u -> bf16 hi/lo mid in microtile layout [e][ktI][mtg][512]
#pragma unroll
  for (int mi = 0; mi < 4; mi++) {
#pragma unroll
    for (int rr = 0; rr < 4; rr++) {
      const int m = tier * 64 + mi * 16 + lg * 4 + rr;
      if (m >= ce) continue;
#pragma unroll
      for (int ni = 0; ni < 2; ni++) {
        const int n = n0 + ni * 16 + l15;
        const float g = accg[mi][ni][rr];
        const float u = accu[mi][ni][rr];
        const float mv = (g / (1.f + expf(-g))) * u;
        const u16 hh = bf16rn(mv);
        const size_t off =
            (((size_t)e * 32 + (n >> 5)) * MTG + (m >> 4)) * 512 +
            (size_t)((m & 15) + ((n >> 3) & 3) * 16) * 8 + (n & 7);
        midh[off] = hh;
        midl[off] = bf16rn(mv - bf16tof(hh));
      }
    }
  }
}

// ---------------------------------------------------------------------------
// Down grouped GEMM — hybrid feed. 256 thr / 4 waves; BM=256, BN=32, K=I
// (32 steps). B (bdh/bdl) staged via global_load_lds into 3 x 4KB buffers
// (VMCNT(9)); A = microtiled mid, direct ping-pong. 24 MFMA / step / wave.
// Grid 1024 = 8e x 64nu x 2tg. Scatter epilogue.
// ---------------------------------------------------------------------------
__global__ __launch_bounds__(256, 2) void down_kernel(
    const u16* __restrict__ midh, const u16* __restrict__ midl,
    const u16* __restrict__ bdh, const u16* __restrict__ bdl,
    const int* __restrict__ cnt, const int* __restrict__ list,
    float* __restrict__ downb)
{
  const int p = blockIdx.x;
  const int L = (p & 7) * 128 + (p >> 3);
  const int e = L >> 7;
  const int rem = L & 127;
  const int nu = rem & 63;
  const int tg = rem >> 6;
  const int n0 = nu * 32;
  int ce = cnt[e]; if (ce > MTG * 16) ce = MTG * 16;
  if (ce == 0) return;
  const int ntiers = (ce + 63) >> 6;
  if (tg == 1 && ntiers <= 4) return;

  __shared__ __align__(16) char ldsB[3 * 4096];

  const int tid = threadIdx.x;
  const int w = tid >> 6, lane = tid & 63;
  const int l15 = lane & 15, lg = lane >> 4;
  const int tier = tg * 4 + w;

  const char* pAh = (const char*)midh + (((size_t)e * 32) * MTG + (size_t)(tier < 6 ? tier * 4 : MTG - 4)) * 1024 + (size_t)lane * 16;
  const char* pAl = (const char*)midl + (((size_t)e * 32) * MTG + (size_t)(tier < 6 ? tier * 4 : MTG - 4)) * 1024 + (size_t)lane * 16;

  // B stage: wave w stages tile idx=w: ntg = w>>1, plane = w&1
  const size_t bbase = (((size_t)e * 32) * 128 + (size_t)(n0 >> 4) + (size_t)(w >> 1)) * 1024 +
                       (size_t)lane * 16;
  const char* sB = (const char*)((w & 1) ? bdl : bdh) + bbase;
  const int dB = w * 1024;

  f32x4 acc[4][2] = {};
  bf16x8 A0[8], A1[8];

  auto stageB = [&](int ts) {
    char* bb = ldsB + (ts % 3) * 4096;
    g2l16(sB + (size_t)ts * 131072, bb + dB);   // 128 ntg * 1KB per kt
  };
  auto aload = [&](bf16x8* As, int ts) {
    const size_t ka = (size_t)ts * (MTG * 1024);
#pragma unroll
    for (int q = 0; q < 4; q++) {
      As[q]     = *(const bf16x8*)(pAh + ka + q * 1024);
      As[4 + q] = *(const bf16x8*)(pAl + ka + q * 1024);
    }
  };
  auto compute = [&](const char* bp, bf16x8* As) {
    bf16x8 bh[2], bl[2];
#pragma unroll
    for (int ni = 0; ni < 2; ni++) {
      bh[ni] = *(const bf16x8*)(bp + (ni * 2 + 0) * 1024 + lane * 16);
      bl[ni] = *(const bf16x8*)(bp + (ni * 2 + 1) * 1024 + lane * 16);
    }
#pragma unroll
    for (int ni = 0; ni < 2; ni++)
#pragma unroll
      for (int mi = 0; mi < 4; mi++) {
        acc[mi][ni] = __builtin_amdgcn_mfma_f32_16x16x32_bf16(As[mi],     bh[ni], acc[mi][ni], 0, 0, 0);
        acc[mi][ni] = __builtin_amdgcn_mfma_f32_16x16x32_bf16(As[mi],     bl[ni], acc[mi][ni], 0, 0, 0);
        acc[mi][ni] = __builtin_amdgcn_mfma_f32_16x16x32_bf16(As[4 + mi], bh[ni], acc[mi][ni], 0, 0, 0);
      }
  };

  stageB(0);
  aload(A0, 0);
  stageB(1);

  for (int t = 0; t < 32; t += 2) {
    aload(A1, t + 1);
    VMCNT(9);
    __builtin_amdgcn_s_barrier();
    if (t + 2 < 32) stageB(t + 2);
    compute(ldsB + (t % 3) * 4096, A0);

    if (t + 2 < 32) aload(A0, t + 2);
    if (t + 1 < 31) { VMCNT(9); } else { VMCNT(0); }
    __builtin_amdgcn_s_barrier();
    if (t + 3 < 32) stageB(t + 3);
    compute(ldsB + ((t + 1) % 3) * 4096, A1);
  }

#pragma unroll
  for (int mi = 0; mi < 4; mi++) {
#pragma unroll
    for (int rr = 0; rr < 4; rr++) {
      const int m = tier * 64 + mi * 16 + lg * 4 + rr;
      if (m >= ce) continue;
      const int ent  = list[e * T + m];
      const int tok  = ent >> 2;
      const int slot = ent & 3;
      float* drow = downb + ((size_t)tok * TK + slot) * H;
#pragma unroll
      for (int ni = 0; ni < 2; ni++) {
        const int n = n0 + ni * 16 + l15;
        drow[n] = acc[mi][ni][rr];
      }
    }
  }
}

// ---------------------------------------------------------------------------
// Combine (unchanged).
// ---------------------------------------------------------------------------
__global__ __launch_bounds__(256) void combine_kernel(
    const float* __restrict__ x, const float* __restrict__ downb,
    const float* __restrict__ wk4, const float* __restrict__ zerow,
    float* __restrict__ out)
{
  const int idx = blockIdx.x * 256 + threadIdx.x;
  const int t   = idx >> 9;
  const int h   = (idx & 511) * 4;

  const float w0 = wk4[t * TK + 0];
  const float w1 = wk4[t * TK + 1];
  const float w2 = wk4[t * TK + 2];
  const float w3 = wk4[t * TK + 3];
  const float zw = zerow[t];

  const float4 xv = *(const float4*)(x + (size_t)t * H + h);
  const float4 d0 = *(const float4*)(downb + ((size_t)t * TK + 0) * H + h);
  const float4 d1 = *(const float4*)(downb + ((size_t)t * TK + 1) * H + h);
  const float4 d2 = *(const float4*)(downb + ((size_t)t * TK + 2) * H + h);
  const float4 d3 = *(const float4*)(downb + ((size_t)t * TK + 3) * H + h);

  float4 o;
  o.x = w0 * d0.x + w1 * d1.x + w2 * d2.x + w3 * d3.x + zw * xv.x;
  o.y = w0 * d0.y + w1 * d1.y + w2 * d2.y + w3 * d3.y + zw * xv.y;
  o.z = w0 * d0.z + w1 * d1.z + w2 * d2.z + w3 * d3.z + zw * xv.z;
  o.w = w0 * d0.w + w1 * d1.w + w2 * d2.w + w3 * d3.w + zw * xv.w;
  *(float4*)(out + (size_t)t * H + h) = o;
}

// ---------------------------------------------------------------------------
// Workspace (~172 MiB): Axh/Axl 12.6 MiB; P = 4 planes x 33.6 MiB
// (bgh/bgl/buh/bul -> later bdh=P0, bdl=P1, downb=P2); midh/midl 6.3 MiB.
// ---------------------------------------------------------------------------
extern "C" void kernel_launch(void* const* d_in, const int* in_sizes, int n_in,
                              void* d_out, int out_size, void* d_ws, size_t ws_size,
                              hipStream_t stream) {
  const float* x    = (const float*)d_in[0];
  const float* rw   = (const float*)d_in[1];
  const float* bias = (const float*)d_in[2];
  const float* wg   = (const float*)d_in[3];
  const float* wu   = (const float*)d_in[4];
  const float* wd   = (const float*)d_in[5];
  float* out = (float*)d_out;

  char* ws = (char*)d_ws;
  size_t off = 0;
  auto alloc = [&](size_t bytes) {
    void* p = ws + off;
    off = (off + bytes + 1023) & ~(size_t)1023;
    return p;
  };
  int*   cnt   = (int*)  alloc(E * sizeof(int));
  int*   list  = (int*)  alloc((size_t)E * T * sizeof(int));
  float* wk4   = (float*)alloc((size_t)T * TK * sizeof(float));
  float* zerow = (float*)alloc((size_t)T * sizeof(float));
  const size_t AXSZ = (size_t)E * 64 * MTG * 512;          // elems
  u16*   Axh   = (u16*)  alloc(AXSZ * sizeof(u16));
  u16*   Axl   = (u16*)  alloc(AXSZ * sizeof(u16));
  constexpr size_t PLANE = (size_t)E * H * I * sizeof(u16);  // 33.6 MB
  char*  P     = (char*) alloc(4 * PLANE);
  u16*   bgh   = (u16*)(P);
  u16*   bgl   = (u16*)(P + PLANE);
  u16*   buh   = (u16*)(P + 2 * PLANE);
  u16*   bul   = (u16*)(P + 3 * PLANE);
  u16*   bdh   = bgh;                      // alias: written after gateup
  u16*   bdl   = bgl;
  float* downb = (float*)(P + 2 * PLANE);  // alias buh: written during down
  const size_t MIDSZ = (size_t)E * 32 * MTG * 512;         // elems
  u16*   midh  = (u16*)  alloc(MIDSZ * sizeof(u16));
  u16*   midl  = (u16*)  alloc(MIDSZ * sizeof(u16));
  (void)ws_size;

  hipMemsetAsync(cnt, 0, E * sizeof(int), stream);

  router_kernel<<<T, 256, 0, stream>>>(x, rw, bias, cnt, list, wk4, zerow);
  prep_a_kernel<<<dim3(64, 8), 256, 0, stream>>>(x, cnt, list, Axh, Axl);
  prep_gu_kernel<<<dim3(1024, 16), 256, 0, stream>>>(
      wg, wu, bgh, bgl, buh, bul);

  gateup_kernel<<<512, 256, 0, stream>>>(
      Axh, Axl, bgh, bgl, buh, bul, cnt, list, midh, midl);

  prep_d_kernel<<<dim3(1024, 8), 256, 0, stream>>>(wd, bdh, bdl);

  down_kernel<<<1024, 256, 0, stream>>>(
      midh, midl, bdh, bdl, cnt, list, downb);
  combine_kernel<<<(T * H / 4) / 256, 256, 0, stream>>>(
      x, downb, wk4, zerow, out);
}

// Round 14
// 199.038 us; speedup vs baseline: 1.3251x; 1.3100x over previous
//
#include <hip/hip_runtime.h>
#include <hip/hip_bf16.h>
#include <math.h>

constexpr int T   = 1024;
constexpr int H   = 2048;
constexpr int I   = 1024;
constexpr int E   = 8;
constexpr int NEZ = 16;   // E + Z
constexpr int TK  = 4;    // TOP_K
constexpr int MTG = 24;   // max m-microtiles per expert (384 rows)

typedef short bf16x8 __attribute__((ext_vector_type(8)));
typedef float f32x4  __attribute__((ext_vector_type(4)));
typedef unsigned short u16;
typedef u16 u16x8 __attribute__((ext_vector_type(8)));

// raw barrier: lgkm drain (LDS writes visible) WITHOUT vmcnt(0) drain --
// keeps the deep global-load pipeline alive across steps (avoids the
// __syncthreads vmcnt-flush stall).
#define SYNC() do { asm volatile("s_waitcnt lgkmcnt(0)" ::: "memory"); \
                    __builtin_amdgcn_s_barrier(); } while (0)

__device__ __forceinline__ u16 bf16rn(float x) {
  unsigned u = __builtin_bit_cast(unsigned, x);
  u = u + 0x7FFFu + ((u >> 16) & 1u);
  return (u16)(u >> 16);
}
__device__ __forceinline__ float bf16tof(u16 h) {
  return __builtin_bit_cast(float, (unsigned)h << 16);
}

// ---------------------------------------------------------------------------
// prep_a: gather+convert x rows per expert into microtile planes
// Axh/Axl [e][kt=64][mtg=MTG][64][8].
// ---------------------------------------------------------------------------
__global__ __launch_bounds__(256) void prep_a_kernel(
    const float* __restrict__ x, const int* __restrict__ cnt,
    const int* __restrict__ list, u16* __restrict__ Axh, u16* __restrict__ Axl)
{
  const int kt = blockIdx.x;   // 0..63
  const int e  = blockIdx.y;   // 0..7
  int ce = cnt[e]; if (ce > MTG * 16) ce = MTG * 16;
  if (ce == 0) return;
  const int tid = threadIdx.x;
  const int w = tid >> 6, lane = tid & 63;
  const int l15 = lane & 15, lg = lane >> 4;

  for (int mtg = w; mtg < MTG; mtg += 4) {
    int r = mtg * 16 + l15; if (r >= ce) r = ce - 1;
    const int tok = list[e * T + r] >> 2;
    const float* src = x + (size_t)tok * H + kt * 32 + lg * 8;
    const float4 v0 = *(const float4*)(src);
    const float4 v1 = *(const float4*)(src + 4);
    const float vv[8] = {v0.x, v0.y, v0.z, v0.w, v1.x, v1.y, v1.z, v1.w};
    u16x8 h8, l8;
#pragma unroll
    for (int j = 0; j < 8; j++) {
      const u16 hh = bf16rn(vv[j]);
      h8[j] = hh;
      l8[j] = bf16rn(vv[j] - bf16tof(hh));
    }
    const size_t off = (((size_t)e * 64 + kt) * MTG + mtg) * 512 + (size_t)lane * 8;
    *(u16x8*)(Axh + off) = h8;
    *(u16x8*)(Axl + off) = l8;
  }
}

// ---------------------------------------------------------------------------
// Router (unchanged, fp32-exact selection).
// ---------------------------------------------------------------------------
__global__ __launch_bounds__(256) void router_kernel(
    const float* __restrict__ x, const float* __restrict__ rw,
    const float* __restrict__ bias, int* __restrict__ cnt,
    int* __restrict__ list, float* __restrict__ wk4,
    float* __restrict__ zerow)
{
  const int t   = blockIdx.x;
  const int tid = threadIdx.x;
  const float* xt = x + (size_t)t * H;

  float acc[NEZ];
#pragma unroll
  for (int e = 0; e < NEZ; e++) acc[e] = 0.f;

  for (int h = tid; h < H; h += 256) {
    const float xv = xt[h];
#pragma unroll
    for (int e = 0; e < NEZ; e++) acc[e] = fmaf(xv, rw[e * H + h], acc[e]);
  }

#pragma unroll
  for (int e = 0; e < NEZ; e++) {
    float v = acc[e];
#pragma unroll
    for (int off = 32; off >= 1; off >>= 1) v += __shfl_down(v, off, 64);
    acc[e] = v;
  }

  __shared__ float red[4][NEZ];
  const int wv = tid >> 6, ln = tid & 63;
  if (ln == 0) {
#pragma unroll
    for (int e = 0; e < NEZ; e++) red[wv][e] = acc[e];
  }
  __syncthreads();

  if (tid == 0) {
    float l[NEZ];
    float mx = -1e30f;
#pragma unroll
    for (int e = 0; e < NEZ; e++) {
      l[e] = red[0][e] + red[1][e] + red[2][e] + red[3][e];
      mx = fmaxf(mx, l[e]);
    }
    float s = 0.f;
#pragma unroll
    for (int e = 0; e < NEZ; e++) { l[e] = expf(l[e] - mx); s += l[e]; }
    const float inv = 1.f / s;
    float sc[NEZ], sel[NEZ];
#pragma unroll
    for (int e = 0; e < NEZ; e++) {
      sc[e]  = l[e] * inv;
      sel[e] = sc[e] + bias[e];
    }
    float zw = 0.f;
#pragma unroll
    for (int k = 0; k < TK; k++) {
      int best = 0; float bv = sel[0];
#pragma unroll
      for (int e = 1; e < NEZ; e++) {
        if (sel[e] > bv) { bv = sel[e]; best = e; }
      }
      sel[best] = -1e30f;
      const float w = sc[best];
      if (best < E) {
        const int pos = atomicAdd(&cnt[best], 1);
        list[best * T + pos] = (t << 2) | k;
        wk4[t * TK + k] = w;
      } else {
        wk4[t * TK + k] = 0.f;
        zw += w;
      }
    }
    zerow[t] = zw;
  }
}

// ---------------------------------------------------------------------------
// Gate+Up grouped GEMM — FUSED fp32->bf16 conversion (no prep pass).
// 256 thr / 4 waves; BM=256 (wave=64m tier), BN=32, BK=32, 64 steps.
// Per step: each thread loads one 8-deep fp32 k-column of wg/wu (8 coalesced
// dwords, 3 slots = 2-iter lookahead), converts hi/lo ONCE, shares via
// 3 x 8KB LDS microtile bufs. A direct global->VGPR from Ax (L2 slab).
// Raw-barrier sync (no vmcnt drain). 48 MFMA / wave / step.
// Grid 512 = 8e x 32nu x 2tg (tg1 exits unless ntiers>4); XCD == expert.
// ---------------------------------------------------------------------------
__global__ __launch_bounds__(256) void gateup_kernel(
    const u16* __restrict__ Axh, const u16* __restrict__ Axl,
    const float* __restrict__ wg, const float* __restrict__ wu,
    const int* __restrict__ cnt, const int* __restrict__ list,
    u16* __restrict__ midh, u16* __restrict__ midl)
{
  const int p = blockIdx.x;
  const int L = (p & 7) * 64 + (p >> 3);   // XCD chunk == expert
  const int e = L >> 6;
  const int rem = L & 63;
  const int nu = rem & 31;
  const int tg = rem >> 5;
  const int n0 = nu * 32;
  int ce = cnt[e]; if (ce > MTG * 16) ce = MTG * 16;
  if (ce == 0) return;
  const int ntiers = (ce + 63) >> 6;
  if (tg == 1 && ntiers <= 4) return;

  __shared__ __align__(16) char ldsB[3][8192];

  const int tid = threadIdx.x;
  const int w = tid >> 6, lane = tid & 63;
  const int l15 = lane & 15, lg = lane >> 4;
  const int tier = tg * 4 + w;
  const bool alive = (tier < ntiers);

  // conversion duty: thread -> (mat, oct, nl) column of 8 k
  const int mat = tid >> 7;            // 0 = gate, 1 = up
  const int oct = (tid >> 5) & 3;      // k-octet
  const int nl  = tid & 31;            // local n
  const int ntgw = nl >> 4;
  const int Lw   = (nl & 15) | (oct << 4);
  const int foh  = ((mat << 2) | ntgw) * 1024 + Lw * 16;   // hi frag offset
  const float* wsrc = (mat ? wu : wg) + (size_t)e * H * I +
                      (size_t)(oct * 8) * I + (size_t)(n0 + nl);

  // A pointers (clamped for dead tiers)
  const int mt0 = (tier <= 5) ? tier * 4 : MTG - 4;
  const char* pAh = (const char*)Axh + (((size_t)e * 64) * MTG + mt0) * 1024 + (size_t)lane * 16;
  const char* pAl = (const char*)Axl + (((size_t)e * 64) * MTG + mt0) * 1024 + (size_t)lane * 16;

  f32x4 accg[4][2] = {};
  f32x4 accu[4][2] = {};
  bf16x8 a0[8], a1[8], a2[8];
  float s0[8], s1[8], s2[8];

#define GU_ISSUE(S, KT) do {                                              \
    const float* ps_ = wsrc + (size_t)(KT) * (32 * (size_t)I);            \
    _Pragma("unroll") for (int j = 0; j < 8; j++) S[j] = ps_[(size_t)j * I]; \
  } while (0)

#define GU_ALOAD(A, KT) do {                                              \
    const size_t ka_ = (size_t)(KT) * (MTG * 1024);                       \
    _Pragma("unroll") for (int q = 0; q < 4; q++) {                       \
      A[q]     = *(const bf16x8*)(pAh + ka_ + q * 1024);                  \
      A[4 + q] = *(const bf16x8*)(pAl + ka_ + q * 1024);                  \
    } } while (0)

#define GU_CONVW(S, WB) do {                                              \
    u16x8 h8_, l8_;                                                       \
    _Pragma("unroll") for (int j = 0; j < 8; j++) {                       \
      const u16 hh_ = bf16rn(S[j]);                                       \
      h8_[j] = hh_; l8_[j] = bf16rn(S[j] - bf16tof(hh_)); }               \
    *(u16x8*)(&ldsB[WB][0] + foh) = h8_;                                  \
    *(u16x8*)(&ldsB[WB][0] + foh + 2048) = l8_;                           \
  } while (0)

#define GU_COMP(RB, A) do {                                               \
    const char* bp_ = &ldsB[RB][0];                                       \
    _Pragma("unroll") for (int ntg = 0; ntg < 2; ntg++) {                 \
      const bf16x8 ggh = *(const bf16x8*)(bp_ + ntg * 1024        + lane * 16); \
      const bf16x8 ggl = *(const bf16x8*)(bp_ + ntg * 1024 + 2048 + lane * 16); \
      const bf16x8 guh = *(const bf16x8*)(bp_ + ntg * 1024 + 4096 + lane * 16); \
      const bf16x8 gul = *(const bf16x8*)(bp_ + ntg * 1024 + 6144 + lane * 16); \
      _Pragma("unroll") for (int mi = 0; mi < 4; mi++) {                  \
        accg[mi][ntg] = __builtin_amdgcn_mfma_f32_16x16x32_bf16(A[mi],     ggh, accg[mi][ntg], 0, 0, 0); \
        accg[mi][ntg] = __builtin_amdgcn_mfma_f32_16x16x32_bf16(A[mi],     ggl, accg[mi][ntg], 0, 0, 0); \
        accg[mi][ntg] = __builtin_amdgcn_mfma_f32_16x16x32_bf16(A[4 + mi], ggh, accg[mi][ntg], 0, 0, 0); \
        accu[mi][ntg] = __builtin_amdgcn_mfma_f32_16x16x32_bf16(A[mi],     guh, accu[mi][ntg], 0, 0, 0); \
        accu[mi][ntg] = __builtin_amdgcn_mfma_f32_16x16x32_bf16(A[mi],     gul, accu[mi][ntg], 0, 0, 0); \
        accu[mi][ntg] = __builtin_amdgcn_mfma_f32_16x16x32_bf16(A[4 + mi], guh, accu[mi][ntg], 0, 0, 0); \
      } } } while (0)

#define GU_BODY(K, SI, AU, AN, SC, RB, WB) do {                           \
    const int k_ = (K);                                                   \
    SYNC();                                                               \
    if (k_ + 3 < 64) GU_ISSUE(SI, k_ + 3);                                \
    if (k_ + 1 < 64) GU_ALOAD(AN, k_ + 1);                                \
    if (alive) GU_COMP(RB, AU);                                           \
    if (k_ + 1 < 64) GU_CONVW(SC, WB);                                    \
  } while (0)

  GU_ISSUE(s0, 0); GU_ISSUE(s1, 1); GU_ISSUE(s2, 2);
  GU_ALOAD(a0, 0);
  GU_CONVW(s0, 0);

  for (int kb = 0; kb < 63; kb += 3) {
    GU_BODY(kb,     s0, a0, a1, s1, 0, 1);
    GU_BODY(kb + 1, s1, a1, a2, s2, 1, 2);
    GU_BODY(kb + 2, s2, a2, a0, s0, 2, 0);
  }
  GU_BODY(63, s0, a0, a1, s1, 0, 1);

#undef GU_ISSUE
#undef GU_ALOAD
#undef GU_CONVW
#undef GU_COMP
#undef GU_BODY

  // epilogue: silu(g)*u -> bf16 hi/lo mid in microtile layout [e][ktI][MTG][512]
#pragma unroll
  for (int mi = 0; mi < 4; mi++) {
#pragma unroll
    for (int rr = 0; rr < 4; rr++) {
      const int m = tier * 64 + mi * 16 + lg * 4 + rr;
      if (m >= ce) continue;
#pragma unroll
      for (int ntg = 0; ntg < 2; ntg++) {
        const int n = n0 + ntg * 16 + l15;
        const float g = accg[mi][ntg][rr];
        const float u = accu[mi][ntg][rr];
        const float mv = (g / (1.f + expf(-g))) * u;
        const u16 hh = bf16rn(mv);
        const size_t off =
            (((size_t)e * 32 + (n >> 5)) * MTG + (m >> 4)) * 512 +
            (size_t)((m & 15) + ((n >> 3) & 3) * 16) * 8 + (n & 7);
        midh[off] = hh;
        midl[off] = bf16rn(mv - bf16tof(hh));
      }
    }
  }
}

// ---------------------------------------------------------------------------
// Down grouped GEMM — FUSED conversion of wd. 256 thr / 4 waves; BM=256,
// BN=64, K=I (32 steps). Thread loads one 8-deep fp32 k-column of wd
// (64-lane-contiguous dwords), converts once, shares via 3 x 8KB LDS.
// A = microtiled mid, direct ping-pong. 48 MFMA / wave / step.
// Grid 512 = 8e x 32nu x 2tg. Scatter epilogue via token list.
// ---------------------------------------------------------------------------
__global__ __launch_bounds__(256) void down_kernel(
    const u16* __restrict__ midh, const u16* __restrict__ midl,
    const float* __restrict__ wd,
    const int* __restrict__ cnt, const int* __restrict__ list,
    float* __restrict__ downb)
{
  const int p = blockIdx.x;
  const int L = (p & 7) * 64 + (p >> 3);
  const int e = L >> 6;
  const int rem = L & 63;
  const int nu = rem & 31;
  const int tg = rem >> 5;
  const int n0 = nu * 64;
  int ce = cnt[e]; if (ce > MTG * 16) ce = MTG * 16;
  if (ce == 0) return;
  const int ntiers = (ce + 63) >> 6;
  if (tg == 1 && ntiers <= 4) return;

  __shared__ __align__(16) char ldsB[3][8192];

  const int tid = threadIdx.x;
  const int w = tid >> 6, lane = tid & 63;
  const int l15 = lane & 15, lg = lane >> 4;
  const int tier = tg * 4 + w;
  const bool alive = (tier < ntiers);

  // conversion duty: thread -> (oct, nl) column of 8 k
  const int oct = tid >> 6;            // == wave
  const int nl  = tid & 63;
  const int ntgw = nl >> 4;            // 0..3
  const int Lw   = (nl & 15) | (oct << 4);
  const int foh  = ntgw * 1024 + Lw * 16;   // hi frag; lo at +4096
  const float* wsrc = wd + (size_t)e * I * H +
                      (size_t)(oct * 8) * H + (size_t)(n0 + nl);

  const int mt0 = (tier <= 5) ? tier * 4 : MTG - 4;
  const char* pAh = (const char*)midh + (((size_t)e * 32) * MTG + mt0) * 1024 + (size_t)lane * 16;
  const char* pAl = (const char*)midl + (((size_t)e * 32) * MTG + mt0) * 1024 + (size_t)lane * 16;

  f32x4 acc[4][4] = {};
  bf16x8 a0[8], a1[8], a2[8];
  float s0[8], s1[8], s2[8];

#define DN_ISSUE(S, KT) do {                                              \
    const float* ps_ = wsrc + (size_t)(KT) * (32 * (size_t)H);            \
    _Pragma("unroll") for (int j = 0; j < 8; j++) S[j] = ps_[(size_t)j * H]; \
  } while (0)

#define DN_ALOAD(A, KT) do {                                              \
    const size_t ka_ = (size_t)(KT) * (MTG * 1024);                       \
    _Pragma("unroll") for (int q = 0; q < 4; q++) {                       \
      A[q]     = *(const bf16x8*)(pAh + ka_ + q * 1024);                  \
      A[4 + q] = *(const bf16x8*)(pAl + ka_ + q * 1024);                  \
    } } while (0)

#define DN_CONVW(S, WB) do {                                              \
    u16x8 h8_, l8_;                                                       \
    _Pragma("unroll") for (int j = 0; j < 8; j++) {                       \
      const u16 hh_ = bf16rn(S[j]);                                       \
      h8_[j] = hh_; l8_[j] = bf16rn(S[j] - bf16tof(hh_)); }               \
    *(u16x8*)(&ldsB[WB][0] + foh) = h8_;                                  \
    *(u16x8*)(&ldsB[WB][0] + foh + 4096) = l8_;                           \
  } while (0)

#define DN_COMP(RB, A) do {                                               \
    const char* bp_ = &ldsB[RB][0];                                       \
    _Pragma("unroll") for (int ntg = 0; ntg < 4; ntg++) {                 \
      const bf16x8 bh = *(const bf16x8*)(bp_ + ntg * 1024        + lane * 16); \
      const bf16x8 bl = *(const bf16x8*)(bp_ + ntg * 1024 + 4096 + lane * 16); \
      _Pragma("unroll") for (int mi = 0; mi < 4; mi++) {                  \
        acc[mi][ntg] = __builtin_amdgcn_mfma_f32_16x16x32_bf16(A[mi],     bh, acc[mi][ntg], 0, 0, 0); \
        acc[mi][ntg] = __builtin_amdgcn_mfma_f32_16x16x32_bf16(A[mi],     bl, acc[mi][ntg], 0, 0, 0); \
        acc[mi][ntg] = __builtin_amdgcn_mfma_f32_16x16x32_bf16(A[4 + mi], bh, acc[mi][ntg], 0, 0, 0); \
      } } } while (0)

#define DN_BODY(K, SI, AU, AN, SC, RB, WB) do {                           \
    const int k_ = (K);                                                   \
    SYNC();                                                               \
    if (k_ + 3 < 32) DN_ISSUE(SI, k_ + 3);                                \
    if (k_ + 1 < 32) DN_ALOAD(AN, k_ + 1);                                \
    if (alive) DN_COMP(RB, AU);                                           \
    if (k_ + 1 < 32) DN_CONVW(SC, WB);                                    \
  } while (0)

  DN_ISSUE(s0, 0); DN_ISSUE(s1, 1); DN_ISSUE(s2, 2);
  DN_ALOAD(a0, 0);
  DN_CONVW(s0, 0);

  for (int kb = 0; kb < 30; kb += 3) {
    DN_BODY(kb,     s0, a0, a1, s1, 0, 1);
    DN_BODY(kb + 1, s1, a1, a2, s2, 1, 2);
    DN_BODY(kb + 2, s2, a2, a0, s0, 2, 0);
  }
  DN_BODY(30, s0, a0, a1, s1, 0, 1);
  DN_BODY(31, s1, a1, a2, s2, 1, 2);

#undef DN_ISSUE
#undef DN_ALOAD
#undef DN_CONVW
#undef DN_COMP
#undef DN_BODY

#pragma unroll
  for (int mi = 0; mi < 4; mi++) {
#pragma unroll
    for (int rr = 0; rr < 4; rr++) {
      const int m = tier * 64 + mi * 16 + lg * 4 + rr;
      if (m >= ce) continue;
      const int ent  = list[e * T + m];
      const int tok  = ent >> 2;
      const int slot = ent & 3;
      float* drow = downb + ((size_t)tok * TK + slot) * H;
#pragma unroll
      for (int ntg = 0; ntg < 4; ntg++) {
        const int n = n0 + ntg * 16 + l15;
        drow[n] = acc[mi][ntg][rr];
      }
    }
  }
}

// ---------------------------------------------------------------------------
// Combine (unchanged).
// ---------------------------------------------------------------------------
__global__ __launch_bounds__(256) void combine_kernel(
    const float* __restrict__ x, const float* __restrict__ downb,
    const float* __restrict__ wk4, const float* __restrict__ zerow,
    float* __restrict__ out)
{
  const int idx = blockIdx.x * 256 + threadIdx.x;
  const int t   = idx >> 9;
  const int h   = (idx & 511) * 4;

  const float w0 = wk4[t * TK + 0];
  const float w1 = wk4[t * TK + 1];
  const float w2 = wk4[t * TK + 2];
  const float w3 = wk4[t * TK + 3];
  const float zw = zerow[t];

  const float4 xv = *(const float4*)(x + (size_t)t * H + h);
  const float4 d0 = *(const float4*)(downb + ((size_t)t * TK + 0) * H + h);
  const float4 d1 = *(const float4*)(downb + ((size_t)t * TK + 1) * H + h);
  const float4 d2 = *(const float4*)(downb + ((size_t)t * TK + 2) * H + h);
  const float4 d3 = *(const float4*)(downb + ((size_t)t * TK + 3) * H + h);

  float4 o;
  o.x = w0 * d0.x + w1 * d1.x + w2 * d2.x + w3 * d3.x + zw * xv.x;
  o.y = w0 * d0.y + w1 * d1.y + w2 * d2.y + w3 * d3.y + zw * xv.y;
  o.z = w0 * d0.z + w1 * d1.z + w2 * d2.z + w3 * d3.z + zw * xv.z;
  o.w = w0 * d0.w + w1 * d1.w + w2 * d2.w + w3 * d3.w + zw * xv.w;
  *(float4*)(out + (size_t)t * H + h) = o;
}

// ---------------------------------------------------------------------------
// Workspace (~70 MiB): cnt/list/wk4/zerow + Axh/Axl 12.6 MiB ea +
// midh/midl 6.3 MiB ea + downb 32 MiB. No weight-plane round trip.
// ---------------------------------------------------------------------------
extern "C" void kernel_launch(void* const* d_in, const int* in_sizes, int n_in,
                              void* d_out, int out_size, void* d_ws, size_t ws_size,
                              hipStream_t stream) {
  const float* x    = (const float*)d_in[0];
  const float* rw   = (const float*)d_in[1];
  const float* bias = (const float*)d_in[2];
  const float* wg   = (const float*)d_in[3];
  const float* wu   = (const float*)d_in[4];
  const float* wd   = (const float*)d_in[5];
  float* out = (float*)d_out;

  char* ws = (char*)d_ws;
  size_t off = 0;
  auto alloc = [&](size_t bytes) {
    void* p = ws + off;
    off = (off + bytes + 1023) & ~(size_t)1023;
    return p;
  };
  int*   cnt   = (int*)  alloc(E * sizeof(int));
  int*   list  = (int*)  alloc((size_t)E * T * sizeof(int));
  float* wk4   = (float*)alloc((size_t)T * TK * sizeof(float));
  float* zerow = (float*)alloc((size_t)T * sizeof(float));
  const size_t AXSZ = (size_t)E * 64 * MTG * 512;          // elems
  u16*   Axh   = (u16*)  alloc(AXSZ * sizeof(u16));
  u16*   Axl   = (u16*)  alloc(AXSZ * sizeof(u16));
  const size_t MIDSZ = (size_t)E * 32 * MTG * 512;         // elems
  u16*   midh  = (u16*)  alloc(MIDSZ * sizeof(u16));
  u16*   midl  = (u16*)  alloc(MIDSZ * sizeof(u16));
  float* downb = (float*)alloc((size_t)T * TK * H * sizeof(float));
  (void)ws_size;

  hipMemsetAsync(cnt, 0, E * sizeof(int), stream);

  router_kernel<<<T, 256, 0, stream>>>(x, rw, bias, cnt, list, wk4, zerow);
  prep_a_kernel<<<dim3(64, 8), 256, 0, stream>>>(x, cnt, list, Axh, Axl);

  gateup_kernel<<<512, 256, 0, stream>>>(
      Axh, Axl, wg, wu, cnt, list, midh, midl);

  down_kernel<<<512, 256, 0, stream>>>(
      midh, midl, wd, cnt, list, downb);

  combine_kernel<<<(T * H / 4) / 256, 256, 0, stream>>>(
      x, downb, wk4, zerow, out);
}